// Round 6
// baseline (888.877 us; speedup 1.0000x reference)
//
#include <hip/hip_runtime.h>

#define BB    16
#define TT    64
#define F0    8
#define NN    100
#define NEX   15
#define F1    32
#define F2    64
#define HRD   64
#define OUTD  5
#define BT    (BB*TT)        // 1024
#define ZELEMS ((size_t)BT*F0*NEX*NN)   // 12,288,000 floats (49.2 MB)

// ===========================================================================
// Head v4 (remap reverted): 4 chains per block share one LDS-staged S[b,t]
// per t-step. Double-buffered Sld/zl -> ONE barrier per step; S[t+1] global
// loads issued before compute (latency hidden under ~800 FMA).
// ===========================================================================
__global__ __launch_bounds__(512) void head_chain(
    const float* __restrict__ x, const float* __restrict__ S,
    float* __restrict__ zbuf) {
  __shared__ float Sld[2][NN * NN];    // 2 x 40 KB
  __shared__ float zl[2][4 * NN * F0]; // 2 x 12.8 KB

  const int blk = blockIdx.x;
  const int b   = blk >> 4;
  const int g   = blk & 15;
  const int tb  = 1 + 4 * g;
  const int te  = min(tb + 17, TT - 1);
  const int tid = threadIdx.x;
  const int m   = tid & 127;
  const int c2  = (tid >> 7) & 1;
  const int f0b = (tid >> 8) * 4;

  auto act = [&](int T, int dst) {
    const int c = T - tb;
    if (c >= 0 && c < 4 && T <= TT - 1 && (c & 1) == c2 && m < NN) {
#pragma unroll
      for (int j = 0; j < 4; ++j)
        zl[dst][c * (NN * F0) + m * F0 + f0b + j] =
            x[((size_t)(b * TT + T - 1) * F0 + f0b + j) * NN + m];
    }
  };

  {
    const float4* Sg = (const float4*)(S + (size_t)(b * TT + tb) * NN * NN);
    float4 R[5];
#pragma unroll
    for (int i = 0; i < 5; ++i) {
      int idx = tid + i * 512; if (idx > 2499) idx = 2499;
      R[i] = Sg[idx];
    }
#pragma unroll
    for (int i = 0; i < 5; ++i) {
      const int idx = tid + i * 512;
      if (idx < 2500) *(float4*)&Sld[0][idx * 4] = R[i];
    }
  }
  act(tb, 0);
  __syncthreads();

  int p = 0;
  for (int t = tb; t <= te; ++t, p ^= 1) {
    const bool more = (t < te);
    float4 Rn[5];
    if (more) {
      const float4* Sg =
          (const float4*)(S + (size_t)(b * TT + t + 1) * NN * NN);
#pragma unroll
      for (int i = 0; i < 5; ++i) {
        int idx = tid + i * 512; if (idx > 2499) idx = 2499;
        Rn[i] = Sg[idx];
      }
    }

    const int t0a = tb + c2;
    const int t0b = tb + c2 + 2;
    const bool a0 = (t >= t0a) && (t <= t0a + 14);
    const bool a1 = (t >= t0b) && (t <= t0b + 14) && (t0b <= TT - 1);

    float acc0[4] = {0.f, 0.f, 0.f, 0.f};
    float acc1[4] = {0.f, 0.f, 0.f, 0.f};
    if (m < NN) {
      const float* Sc = Sld[p];
      const float* zA = &zl[p][c2 * (NN * F0) + f0b];
      const float* zB = &zl[p][(c2 + 2) * (NN * F0) + f0b];
      if (a0 && a1) {
#pragma unroll 10
        for (int n = 0; n < NN; ++n) {
          const float s = Sc[n * NN + m];
          const float4 z0 = *(const float4*)&zA[n * F0];
          const float4 z1 = *(const float4*)&zB[n * F0];
          acc0[0] += z0.x * s; acc0[1] += z0.y * s;
          acc0[2] += z0.z * s; acc0[3] += z0.w * s;
          acc1[0] += z1.x * s; acc1[1] += z1.y * s;
          acc1[2] += z1.z * s; acc1[3] += z1.w * s;
        }
      } else if (a0) {
#pragma unroll 10
        for (int n = 0; n < NN; ++n) {
          const float s = Sc[n * NN + m];
          const float4 z0 = *(const float4*)&zA[n * F0];
          acc0[0] += z0.x * s; acc0[1] += z0.y * s;
          acc0[2] += z0.z * s; acc0[3] += z0.w * s;
        }
      } else if (a1) {
#pragma unroll 10
        for (int n = 0; n < NN; ++n) {
          const float s = Sc[n * NN + m];
          const float4 z1 = *(const float4*)&zB[n * F0];
          acc1[0] += z1.x * s; acc1[1] += z1.y * s;
          acc1[2] += z1.z * s; acc1[3] += z1.w * s;
        }
      }
    }

    if (m < NN) {
      if (a0) {
        *(float4*)&zl[p ^ 1][c2 * (NN * F0) + m * F0 + f0b] =
            make_float4(acc0[0], acc0[1], acc0[2], acc0[3]);
        const int k = t - t0a;
#pragma unroll
        for (int j = 0; j < 4; ++j)
          zbuf[(((size_t)(b * TT + t) * F0 + f0b + j) * NEX + k) * NN + m] =
              acc0[j];
      }
      if (a1) {
        *(float4*)&zl[p ^ 1][(c2 + 2) * (NN * F0) + m * F0 + f0b] =
            make_float4(acc1[0], acc1[1], acc1[2], acc1[3]);
        const int k = t - t0b;
#pragma unroll
        for (int j = 0; j < 4; ++j)
          zbuf[(((size_t)(b * TT + t) * F0 + f0b + j) * NEX + k) * NN + m] =
              acc1[j];
      }
    }
    act(t + 1, p ^ 1);
    if (more) {
#pragma unroll
      for (int i = 0; i < 5; ++i) {
        const int idx = tid + i * 512;
        if (idx < 2500) *(float4*)&Sld[p ^ 1][idx * 4] = Rn[i];
      }
    }
    __syncthreads();
  }
}

// ===========================================================================
// Tail v6: block = (bt, n-half of 50). 256 threads = 4 waves; lane = tid&63
// (n-slot, 50 active), sg = tid>>6 = wave id (weight indices wave-uniform).
// LDS 38.4 KB -> 4 blocks/CU (with VGPR <=128 via launch_bounds(256,4));
// 4 independent barrier domains per CU hide each other's stalls.
// LDS (floats): y1[32][6][50] in [0,9600); then y2[128][50] overwrites
// [0,6400) and h[64][50] -> [6400,9600).
// ===========================================================================
__global__ __launch_bounds__(256, 4) void tail_fused4(
    const float* __restrict__ x, const float* __restrict__ zbuf,
    const float* __restrict__ w1,  const float* __restrict__ b1,
    const float* __restrict__ w2,  const float* __restrict__ b2,
    const float* __restrict__ fw1, const float* __restrict__ fb1,
    const float* __restrict__ fw2, const float* __restrict__ fb2,
    float* __restrict__ out) {
  __shared__ float lds[9600];          // 38.4 KB

  const int blk = blockIdx.x;          // 2048
  const int bt  = blk >> 1;
  const int n0  = (blk & 1) * 50;
  const int t   = bt & (TT - 1);
  const int tid = threadIdx.x;
  const int ln  = tid & 63;            // n-slot, active if < 50
  const int sg  = tid >> 6;            // wave id 0..3
  const int n   = n0 + ln;

  // ---- conv1 (8ch,K=4)+ReLU+pool2 -> y1, two co-halves of 4 per wave ----
  if (ln < 50) {
#pragma unroll 1
    for (int h = 0; h < 2; ++h) {
      const int c0 = sg * 8 + h * 4;
      float acc[4][12];
#pragma unroll
      for (int j = 0; j < 4; ++j) {
        const float bias = b1[c0 + j];
#pragma unroll
        for (int l = 0; l < 12; ++l) acc[j][l] = bias;
      }
#pragma unroll 1
      for (int ci = 0; ci < F0; ++ci) {
        float zv[15];
        zv[0] = x[((size_t)bt * F0 + ci) * NN + n];
#pragma unroll
        for (int k = 1; k < 15; ++k)
          zv[k] = (k <= t)
              ? zbuf[(((size_t)bt * F0 + ci) * NEX + (k - 1)) * NN + n]
              : 0.f;
#pragma unroll
        for (int j = 0; j < 4; ++j)
#pragma unroll
          for (int kk = 0; kk < 4; ++kk) {
            const float w = w1[((c0 + j) * F0 + ci) * 4 + kk];  // uniform
#pragma unroll
            for (int l = 0; l < 12; ++l) acc[j][l] += zv[l + kk] * w;
          }
      }
#pragma unroll
      for (int j = 0; j < 4; ++j)
#pragma unroll
        for (int p = 0; p < 6; ++p)
          lds[(c0 + j) * 300 + p * 50 + ln] =
              fmaxf(fmaxf(acc[j][2 * p], acc[j][2 * p + 1]), 0.f);
    }
  }
  __syncthreads();

  // ---- conv2 (32ch,K=3)+ReLU+pool2: accumulate in regs from y1 ----
  float acc2[16][4];
  {
#pragma unroll
    for (int j = 0; j < 16; ++j) {
      const float bb = b2[sg * 16 + j];
#pragma unroll
      for (int l = 0; l < 4; ++l) acc2[j][l] = bb;
    }
    if (ln < 50) {
#pragma unroll 1
      for (int ci = 0; ci < F1; ++ci) {
        float yv[6];
#pragma unroll
        for (int l = 0; l < 6; ++l) yv[l] = lds[ci * 300 + l * 50 + ln];
#pragma unroll
        for (int j = 0; j < 16; ++j)
#pragma unroll
          for (int kk = 0; kk < 3; ++kk) {
            const float w = w2[((sg * 16 + j) * F1 + ci) * 3 + kk];  // uniform
#pragma unroll
            for (int l = 0; l < 4; ++l) acc2[j][l] += yv[l + kk] * w;
          }
      }
    }
  }
  __syncthreads();                     // all y1 reads done

  // ---- y2 overwrites lds[0,6400) ----
  if (ln < 50) {
#pragma unroll
    for (int j = 0; j < 16; ++j) {
      const int d0 = (sg * 16 + j) * 2;
      lds[(d0 + 0) * 50 + ln] = fmaxf(fmaxf(acc2[j][0], acc2[j][1]), 0.f);
      lds[(d0 + 1) * 50 + ln] = fmaxf(fmaxf(acc2[j][2], acc2[j][3]), 0.f);
    }
  }
  __syncthreads();

  // ---- fc1 (128->64,ReLU) -> h in lds[6400,9600), one 64-reg half live ----
  if (ln < 50) {
    float hacc[16];
#pragma unroll
    for (int jj = 0; jj < 16; ++jj) hacc[jj] = fb1[sg * 16 + jj];
#pragma unroll 1
    for (int half = 0; half < 2; ++half) {
      float v[64];
#pragma unroll
      for (int dd = 0; dd < 64; ++dd) v[dd] = lds[(half * 64 + dd) * 50 + ln];
#pragma unroll
      for (int jj = 0; jj < 16; ++jj) {
        const float* wr = fw1 + (sg * 16 + jj) * 128 + half * 64;  // uniform
        float s0 = 0.f, s1 = 0.f, s2 = 0.f, s3 = 0.f;
#pragma unroll
        for (int dd = 0; dd < 64; dd += 4) {
          s0 += v[dd + 0] * wr[dd + 0];
          s1 += v[dd + 1] * wr[dd + 1];
          s2 += v[dd + 2] * wr[dd + 2];
          s3 += v[dd + 3] * wr[dd + 3];
        }
        hacc[jj] += (s0 + s1) + (s2 + s3);
      }
    }
#pragma unroll
    for (int jj = 0; jj < 16; ++jj)
      lds[6400 + (sg * 16 + jj) * 50 + ln] = fmaxf(hacc[jj], 0.f);
  }
  __syncthreads();

  // ---- fc2 (64->5) -> out (250 of 256 threads) ----
  if (tid < OUTD * 50) {
    const int q  = tid / 50;
    const int n2 = tid - q * 50;
    float o = fb2[q];
#pragma unroll
    for (int j = 0; j < HRD; ++j)
      o += lds[6400 + j * 50 + n2] * fw2[q * HRD + j];
    out[((size_t)bt * OUTD + q) * NN + n0 + n2] = o;
  }
}

// ===========================================================================
extern "C" void kernel_launch(void* const* d_in, const int* in_sizes, int n_in,
                              void* d_out, int out_size, void* d_ws,
                              size_t ws_size, hipStream_t stream) {
  const float* x   = (const float*)d_in[0];
  const float* S   = (const float*)d_in[1];
  const float* w1  = (const float*)d_in[2];
  const float* b1  = (const float*)d_in[3];
  const float* w2  = (const float*)d_in[4];
  const float* b2  = (const float*)d_in[5];
  const float* fw1 = (const float*)d_in[6];
  const float* fb1 = (const float*)d_in[7];
  const float* fw2 = (const float*)d_in[8];
  const float* fb2 = (const float*)d_in[9];

  float* zbuf = (float*)d_ws;          // 49.2 MB
  float* outp = (float*)d_out;

  head_chain<<<BB * 16, 512, 0, stream>>>(x, S, zbuf);
  tail_fused4<<<2 * BT, 256, 0, stream>>>(x, zbuf, w1, b1, w2, b2, fw1, fb1,
                                          fw2, fb2, outp);
}

// Round 7
// 387.343 us; speedup vs baseline: 2.2948x; 2.2948x over previous
//
#include <hip/hip_runtime.h>

#define BB    16
#define TT    64
#define F0    8
#define NN    100
#define NEX   15
#define F1    32
#define F2    64
#define HRD   64
#define OUTD  5
#define BT    (BB*TT)        // 1024
#define ZELEMS ((size_t)BT*F0*NEX*NN)   // 12,288,000 floats (49.2 MB)

// ===========================================================================
// Head v4: 4 chains per block share one LDS-staged S[b,t] per t-step.
// Double-buffered Sld/zl -> ONE barrier per step; S[t+1] global loads issued
// before compute (latency hidden under ~800 FMA).
// ===========================================================================
__global__ __launch_bounds__(512) void head_chain(
    const float* __restrict__ x, const float* __restrict__ S,
    float* __restrict__ zbuf) {
  __shared__ float Sld[2][NN * NN];    // 2 x 40 KB
  __shared__ float zl[2][4 * NN * F0]; // 2 x 12.8 KB

  const int blk = blockIdx.x;
  const int b   = blk >> 4;
  const int g   = blk & 15;
  const int tb  = 1 + 4 * g;
  const int te  = min(tb + 17, TT - 1);
  const int tid = threadIdx.x;
  const int m   = tid & 127;
  const int c2  = (tid >> 7) & 1;
  const int f0b = (tid >> 8) * 4;

  auto act = [&](int T, int dst) {
    const int c = T - tb;
    if (c >= 0 && c < 4 && T <= TT - 1 && (c & 1) == c2 && m < NN) {
#pragma unroll
      for (int j = 0; j < 4; ++j)
        zl[dst][c * (NN * F0) + m * F0 + f0b + j] =
            x[((size_t)(b * TT + T - 1) * F0 + f0b + j) * NN + m];
    }
  };

  {
    const float4* Sg = (const float4*)(S + (size_t)(b * TT + tb) * NN * NN);
    float4 R[5];
#pragma unroll
    for (int i = 0; i < 5; ++i) {
      int idx = tid + i * 512; if (idx > 2499) idx = 2499;
      R[i] = Sg[idx];
    }
#pragma unroll
    for (int i = 0; i < 5; ++i) {
      const int idx = tid + i * 512;
      if (idx < 2500) *(float4*)&Sld[0][idx * 4] = R[i];
    }
  }
  act(tb, 0);
  __syncthreads();

  int p = 0;
  for (int t = tb; t <= te; ++t, p ^= 1) {
    const bool more = (t < te);
    float4 Rn[5];
    if (more) {
      const float4* Sg =
          (const float4*)(S + (size_t)(b * TT + t + 1) * NN * NN);
#pragma unroll
      for (int i = 0; i < 5; ++i) {
        int idx = tid + i * 512; if (idx > 2499) idx = 2499;
        Rn[i] = Sg[idx];
      }
    }

    const int t0a = tb + c2;
    const int t0b = tb + c2 + 2;
    const bool a0 = (t >= t0a) && (t <= t0a + 14);
    const bool a1 = (t >= t0b) && (t <= t0b + 14) && (t0b <= TT - 1);

    float acc0[4] = {0.f, 0.f, 0.f, 0.f};
    float acc1[4] = {0.f, 0.f, 0.f, 0.f};
    if (m < NN) {
      const float* Sc = Sld[p];
      const float* zA = &zl[p][c2 * (NN * F0) + f0b];
      const float* zB = &zl[p][(c2 + 2) * (NN * F0) + f0b];
      if (a0 && a1) {
#pragma unroll 10
        for (int n = 0; n < NN; ++n) {
          const float s = Sc[n * NN + m];
          const float4 z0 = *(const float4*)&zA[n * F0];
          const float4 z1 = *(const float4*)&zB[n * F0];
          acc0[0] += z0.x * s; acc0[1] += z0.y * s;
          acc0[2] += z0.z * s; acc0[3] += z0.w * s;
          acc1[0] += z1.x * s; acc1[1] += z1.y * s;
          acc1[2] += z1.z * s; acc1[3] += z1.w * s;
        }
      } else if (a0) {
#pragma unroll 10
        for (int n = 0; n < NN; ++n) {
          const float s = Sc[n * NN + m];
          const float4 z0 = *(const float4*)&zA[n * F0];
          acc0[0] += z0.x * s; acc0[1] += z0.y * s;
          acc0[2] += z0.z * s; acc0[3] += z0.w * s;
        }
      } else if (a1) {
#pragma unroll 10
        for (int n = 0; n < NN; ++n) {
          const float s = Sc[n * NN + m];
          const float4 z1 = *(const float4*)&zB[n * F0];
          acc1[0] += z1.x * s; acc1[1] += z1.y * s;
          acc1[2] += z1.z * s; acc1[3] += z1.w * s;
        }
      }
    }

    if (m < NN) {
      if (a0) {
        *(float4*)&zl[p ^ 1][c2 * (NN * F0) + m * F0 + f0b] =
            make_float4(acc0[0], acc0[1], acc0[2], acc0[3]);
        const int k = t - t0a;
#pragma unroll
        for (int j = 0; j < 4; ++j)
          zbuf[(((size_t)(b * TT + t) * F0 + f0b + j) * NEX + k) * NN + m] =
              acc0[j];
      }
      if (a1) {
        *(float4*)&zl[p ^ 1][(c2 + 2) * (NN * F0) + m * F0 + f0b] =
            make_float4(acc1[0], acc1[1], acc1[2], acc1[3]);
        const int k = t - t0b;
#pragma unroll
        for (int j = 0; j < 4; ++j)
          zbuf[(((size_t)(b * TT + t) * F0 + f0b + j) * NEX + k) * NN + m] =
              acc1[j];
      }
    }
    act(t + 1, p ^ 1);
    if (more) {
#pragma unroll
      for (int i = 0; i < 5; ++i) {
        const int idx = tid + i * 512;
        if (idx < 2500) *(float4*)&Sld[p ^ 1][idx * 4] = Rn[i];
      }
    }
    __syncthreads();
  }
}

// ===========================================================================
// Tail v7: block = (bt, n-half of 50). 256 threads = 4 waves; ln = tid&63
// (n-slot, 50 active), sg = tid>>6 = wave id (weight indices wave-uniform).
// LDS 38.4 KB; NO min-waves hint (R4/R6 proved it forces VGPR=64 + spills).
// Natural VGPR ~120 <= 128 -> 4 waves/SIMD possible; ~3 blocks/CU by LDS.
// LDS (floats): y1[32][6][50] in [0,9600); then y2[128][50] overwrites
// [0,6400) and h[64][50] -> [6400,9600).
// ===========================================================================
__global__ __launch_bounds__(256) void tail_fused4(
    const float* __restrict__ x, const float* __restrict__ zbuf,
    const float* __restrict__ w1,  const float* __restrict__ b1,
    const float* __restrict__ w2,  const float* __restrict__ b2,
    const float* __restrict__ fw1, const float* __restrict__ fb1,
    const float* __restrict__ fw2, const float* __restrict__ fb2,
    float* __restrict__ out) {
  __shared__ float lds[9600];          // 38.4 KB

  const int blk = blockIdx.x;          // 2048
  const int bt  = blk >> 1;
  const int n0  = (blk & 1) * 50;
  const int t   = bt & (TT - 1);
  const int tid = threadIdx.x;
  const int ln  = tid & 63;            // n-slot, active if < 50
  const int sg  = tid >> 6;            // wave id 0..3
  const int n   = n0 + ln;

  // ---- conv1 (8ch,K=4)+ReLU+pool2 -> y1, two co-halves of 4 per wave ----
  if (ln < 50) {
#pragma unroll 1
    for (int h = 0; h < 2; ++h) {
      const int c0 = sg * 8 + h * 4;
      float acc[4][12];
#pragma unroll
      for (int j = 0; j < 4; ++j) {
        const float bias = b1[c0 + j];
#pragma unroll
        for (int l = 0; l < 12; ++l) acc[j][l] = bias;
      }
#pragma unroll 1
      for (int ci = 0; ci < F0; ++ci) {
        float zv[15];
        zv[0] = x[((size_t)bt * F0 + ci) * NN + n];
#pragma unroll
        for (int k = 1; k < 15; ++k)
          zv[k] = (k <= t)
              ? zbuf[(((size_t)bt * F0 + ci) * NEX + (k - 1)) * NN + n]
              : 0.f;
#pragma unroll
        for (int j = 0; j < 4; ++j)
#pragma unroll
          for (int kk = 0; kk < 4; ++kk) {
            const float w = w1[((c0 + j) * F0 + ci) * 4 + kk];  // uniform
#pragma unroll
            for (int l = 0; l < 12; ++l) acc[j][l] += zv[l + kk] * w;
          }
      }
#pragma unroll
      for (int j = 0; j < 4; ++j)
#pragma unroll
        for (int p = 0; p < 6; ++p)
          lds[(c0 + j) * 300 + p * 50 + ln] =
              fmaxf(fmaxf(acc[j][2 * p], acc[j][2 * p + 1]), 0.f);
    }
  }
  __syncthreads();

  // ---- conv2 (32ch,K=3)+ReLU+pool2: accumulate in regs from y1 ----
  float acc2[16][4];
  {
#pragma unroll
    for (int j = 0; j < 16; ++j) {
      const float bb = b2[sg * 16 + j];
#pragma unroll
      for (int l = 0; l < 4; ++l) acc2[j][l] = bb;
    }
    if (ln < 50) {
#pragma unroll 1
      for (int ci = 0; ci < F1; ++ci) {
        float yv[6];
#pragma unroll
        for (int l = 0; l < 6; ++l) yv[l] = lds[ci * 300 + l * 50 + ln];
#pragma unroll
        for (int j = 0; j < 16; ++j)
#pragma unroll
          for (int kk = 0; kk < 3; ++kk) {
            const float w = w2[((sg * 16 + j) * F1 + ci) * 3 + kk];  // uniform
#pragma unroll
            for (int l = 0; l < 4; ++l) acc2[j][l] += yv[l + kk] * w;
          }
      }
    }
  }
  __syncthreads();                     // all y1 reads done

  // ---- y2 overwrites lds[0,6400) ----
  if (ln < 50) {
#pragma unroll
    for (int j = 0; j < 16; ++j) {
      const int d0 = (sg * 16 + j) * 2;
      lds[(d0 + 0) * 50 + ln] = fmaxf(fmaxf(acc2[j][0], acc2[j][1]), 0.f);
      lds[(d0 + 1) * 50 + ln] = fmaxf(fmaxf(acc2[j][2], acc2[j][3]), 0.f);
    }
  }
  __syncthreads();

  // ---- fc1 (128->64,ReLU) -> h in lds[6400,9600), one 64-reg half live ----
  if (ln < 50) {
    float hacc[16];
#pragma unroll
    for (int jj = 0; jj < 16; ++jj) hacc[jj] = fb1[sg * 16 + jj];
#pragma unroll 1
    for (int half = 0; half < 2; ++half) {
      float v[64];
#pragma unroll
      for (int dd = 0; dd < 64; ++dd) v[dd] = lds[(half * 64 + dd) * 50 + ln];
#pragma unroll
      for (int jj = 0; jj < 16; ++jj) {
        const float* wr = fw1 + (sg * 16 + jj) * 128 + half * 64;  // uniform
        float s0 = 0.f, s1 = 0.f, s2 = 0.f, s3 = 0.f;
#pragma unroll
        for (int dd = 0; dd < 64; dd += 4) {
          s0 += v[dd + 0] * wr[dd + 0];
          s1 += v[dd + 1] * wr[dd + 1];
          s2 += v[dd + 2] * wr[dd + 2];
          s3 += v[dd + 3] * wr[dd + 3];
        }
        hacc[jj] += (s0 + s1) + (s2 + s3);
      }
    }
#pragma unroll
    for (int jj = 0; jj < 16; ++jj)
      lds[6400 + (sg * 16 + jj) * 50 + ln] = fmaxf(hacc[jj], 0.f);
  }
  __syncthreads();

  // ---- fc2 (64->5) -> out (250 of 256 threads) ----
  if (tid < OUTD * 50) {
    const int q  = tid / 50;
    const int n2 = tid - q * 50;
    float o = fb2[q];
#pragma unroll
    for (int j = 0; j < HRD; ++j)
      o += lds[6400 + j * 50 + n2] * fw2[q * HRD + j];
    out[((size_t)bt * OUTD + q) * NN + n0 + n2] = o;
  }
}

// ===========================================================================
extern "C" void kernel_launch(void* const* d_in, const int* in_sizes, int n_in,
                              void* d_out, int out_size, void* d_ws,
                              size_t ws_size, hipStream_t stream) {
  const float* x   = (const float*)d_in[0];
  const float* S   = (const float*)d_in[1];
  const float* w1  = (const float*)d_in[2];
  const float* b1  = (const float*)d_in[3];
  const float* w2  = (const float*)d_in[4];
  const float* b2  = (const float*)d_in[5];
  const float* fw1 = (const float*)d_in[6];
  const float* fb1 = (const float*)d_in[7];
  const float* fw2 = (const float*)d_in[8];
  const float* fb2 = (const float*)d_in[9];

  float* zbuf = (float*)d_ws;          // 49.2 MB
  float* outp = (float*)d_out;

  head_chain<<<BB * 16, 512, 0, stream>>>(x, S, zbuf);
  tail_fused4<<<2 * BT, 256, 0, stream>>>(x, zbuf, w1, b1, w2, b2, fw1, fb1,
                                          fw2, fb2, outp);
}